// Round 1
// baseline (846.952 us; speedup 1.0000x reference)
//
#include <hip/hip_runtime.h>

#define BL    16384   // B*L
#define LQ    4096    // L
#define KNB   32
#define DU    128
#define DL    64

typedef unsigned int uint;

static __device__ __forceinline__ uint f2bf(float f) {
    uint x = __float_as_uint(f);
    x += 0x7fffu + ((x >> 16) & 1u);   // round-to-nearest-even
    return x >> 16;
}
static __device__ __forceinline__ float bflo(uint p) { return __uint_as_float(p << 16); }
static __device__ __forceinline__ float bfhi(uint p) { return __uint_as_float(p & 0xffff0000u); }

// ---------------- Kernel 1: fused QKV projection (fp32) ----------------
// grid = BL/16 blocks, 256 threads. Each block: 16 rows, thread = (row-half, col).
__global__ __launch_bounds__(256) void qkv_kernel(
    const float* __restrict__ x, const float* __restrict__ Wq,
    const float* __restrict__ Wk, const float* __restrict__ Wv,
    float* __restrict__ qb, float* __restrict__ kb, float* __restrict__ vb)
{
    __shared__ __attribute__((aligned(16))) float xs[16][128];
    const int tid  = threadIdx.x;
    const int row0 = blockIdx.x * 16;

    for (int e = tid; e < 16 * 128; e += 256)
        xs[e >> 7][e & 127] = x[row0 * 128 + e];
    __syncthreads();

    const int c  = tid & 127;
    const int rh = tid >> 7;          // 0/1 -> rows rh*8 .. rh*8+7
    float aq[8], ak[8], av[8];
    #pragma unroll
    for (int i = 0; i < 8; ++i) { aq[i] = 0.f; ak[i] = 0.f; av[i] = 0.f; }

    for (int u4 = 0; u4 < 32; ++u4) {
        float4 xv[8];
        #pragma unroll
        for (int i = 0; i < 8; ++i)
            xv[i] = ((const float4*)xs[rh * 8 + i])[u4];
        #pragma unroll
        for (int s = 0; s < 4; ++s) {
            const int u = u4 * 4 + s;
            const float wq = Wq[u * 128 + c];
            const float wk = Wk[u * 128 + c];
            const float wv = Wv[u * 128 + c];
            #pragma unroll
            for (int i = 0; i < 8; ++i) {
                const float xe = (s == 0) ? xv[i].x : (s == 1) ? xv[i].y : (s == 2) ? xv[i].z : xv[i].w;
                aq[i] = fmaf(xe, wq, aq[i]);
                ak[i] = fmaf(xe, wk, ak[i]);
                av[i] = fmaf(xe, wv, av[i]);
            }
        }
    }
    #pragma unroll
    for (int i = 0; i < 8; ++i) {
        const int r = row0 + rh * 8 + i;
        qb[r * 128 + c] = aq[i];
        kb[r * 128 + c] = ak[i];
        vb[r * 128 + c] = av[i];
    }
}

// ---------------- Kernel 2: fused neighbor-attention ----------------
// grid = BL/8 blocks, 512 threads (8 waves). Block handles 8 positions serially.
// Per position: wave w owns neighbors k = w*4 .. w*4+3 (per-wave-private LDS slices),
// single-pass softmax (exp without max; logits are O(10) max -> safe in fp32).
__global__ __launch_bounds__(512) void attn_kernel(
    const float* __restrict__ pos, const int* __restrict__ nn_idx,
    const float* __restrict__ qb, const float* __restrict__ kb,
    const float* __restrict__ vb, const float* __restrict__ Wa0,
    const float* __restrict__ Wa1, float* __restrict__ out)
{
    __shared__ __attribute__((aligned(16))) uint  wa0p[32][64][2];   // [u4][j][pair], 4 bf16 ea
    __shared__ __attribute__((aligned(16))) uint  wa1p[16][128][2];  // [j4][c][pair]
    __shared__ __attribute__((aligned(16))) float qs[128];
    __shared__ int   idxs[32];
    __shared__ __attribute__((aligned(16))) float tw[8][128];        // per-wave t = q - k_n + pos
    __shared__ __attribute__((aligned(16))) float vpw[8][128];       // per-wave v_n + pos
    __shared__ __attribute__((aligned(16))) float hb[8][64];         // per-wave hidden
    __shared__ __attribute__((aligned(16))) float part[8][2][128];   // per-wave {sumexp, outsum}

    const int tid  = threadIdx.x;
    const int w    = tid >> 6;
    const int lane = tid & 63;

    // Pack Wa0 [128][64] -> bf16 pairs, blocked over u.
    for (int e = tid; e < 32 * 64 * 2; e += 512) {
        const int u4 = e >> 7, j = (e >> 1) & 63, pp = e & 1;
        const int u  = u4 * 4 + pp * 2;
        wa0p[u4][j][pp] = f2bf(Wa0[u * 64 + j]) | (f2bf(Wa0[(u + 1) * 64 + j]) << 16);
    }
    // Pack Wa1 [64][128] -> bf16 pairs, blocked over j.
    for (int e = tid; e < 16 * 128 * 2; e += 512) {
        const int j4 = e >> 8, c = (e >> 1) & 127, pp = e & 1;
        const int j  = j4 * 4 + pp * 2;
        wa1p[j4][c][pp] = f2bf(Wa1[j * 128 + c]) | (f2bf(Wa1[(j + 1) * 128 + c]) << 16);
    }

    const int p0 = blockIdx.x * 8;
    for (int pi = 0; pi < 8; ++pi) {
        const int p     = p0 + pi;
        const int bbase = (p >> 12) << 12;   // b * L
        __syncthreads();                     // guard qs/idxs/part reuse
        if (tid < 128)       qs[tid] = qb[p * 128 + tid];
        else if (tid < 160)  idxs[tid - 128] = nn_idx[p * 32 + (tid - 128)];
        __syncthreads();

        float se0 = 0.f, se1 = 0.f, o0 = 0.f, o1 = 0.f;
        for (int n = 0; n < 4; ++n) {
            const int k    = w * 4 + n;
            const int idx  = idxs[k];
            const int krow = (bbase + idx) * 128;
            const int prow = (p * 32 + k) * 128;

            // stage t and v+pos for this neighbor (wave-private)
            const float pv0 = pos[prow + lane],      pv1 = pos[prow + 64 + lane];
            const float kv0 = kb[krow + lane],       kv1 = kb[krow + 64 + lane];
            const float vv0 = vb[krow + lane],       vv1 = vb[krow + 64 + lane];
            tw[w][lane]       = qs[lane]      - kv0 + pv0;
            tw[w][64 + lane]  = qs[64 + lane] - kv1 + pv1;
            vpw[w][lane]      = vv0 + pv0;
            vpw[w][64 + lane] = vv1 + pv1;
            __asm__ volatile("s_waitcnt lgkmcnt(0)" ::: "memory");

            // hidden: h[j] = relu(sum_u t[u] * Wa0[u][j]),  lane = j
            float hacc = 0.f;
            #pragma unroll 8
            for (int u4 = 0; u4 < 32; ++u4) {
                const float4 t4 = ((const float4*)tw[w])[u4];
                const uint2  wp = *(const uint2*)&wa0p[u4][lane][0];
                hacc = fmaf(t4.x, bflo(wp.x), hacc);
                hacc = fmaf(t4.y, bfhi(wp.x), hacc);
                hacc = fmaf(t4.z, bflo(wp.y), hacc);
                hacc = fmaf(t4.w, bfhi(wp.y), hacc);
            }
            hb[w][lane] = fmaxf(hacc, 0.f);
            __asm__ volatile("s_waitcnt lgkmcnt(0)" ::: "memory");

            // logits: a[c] = sum_j h[j] * Wa1[j][c],  lane covers c=lane and c=lane+64
            float a0 = 0.f, a1 = 0.f;
            #pragma unroll 8
            for (int j4 = 0; j4 < 16; ++j4) {
                const float4 h4  = ((const float4*)hb[w])[j4];
                const uint2  w1a = *(const uint2*)&wa1p[j4][lane][0];
                const uint2  w1b = *(const uint2*)&wa1p[j4][lane + 64][0];
                a0 = fmaf(h4.x, bflo(w1a.x), a0); a0 = fmaf(h4.y, bfhi(w1a.x), a0);
                a0 = fmaf(h4.z, bflo(w1a.y), a0); a0 = fmaf(h4.w, bfhi(w1a.y), a0);
                a1 = fmaf(h4.x, bflo(w1b.x), a1); a1 = fmaf(h4.y, bfhi(w1b.x), a1);
                a1 = fmaf(h4.z, bflo(w1b.y), a1); a1 = fmaf(h4.w, bfhi(w1b.y), a1);
            }
            const float e0 = __expf(a0), e1 = __expf(a1);
            se0 += e0; se1 += e1;
            o0 = fmaf(e0, vpw[w][lane],      o0);
            o1 = fmaf(e1, vpw[w][lane + 64], o1);
        }
        part[w][0][lane]      = se0;
        part[w][0][lane + 64] = se1;
        part[w][1][lane]      = o0;
        part[w][1][lane + 64] = o1;
        __syncthreads();

        if (tid < 128) {
            float se = 0.f, oo = 0.f;
            #pragma unroll
            for (int ww = 0; ww < 8; ++ww) { se += part[ww][0][tid]; oo += part[ww][1][tid]; }
            out[p * 128 + tid] = oo / se;
        }
    }
}

extern "C" void kernel_launch(void* const* d_in, const int* in_sizes, int n_in,
                              void* d_out, int out_size, void* d_ws, size_t ws_size,
                              hipStream_t stream) {
    const float* x    = (const float*)d_in[0];
    const float* pos  = (const float*)d_in[1];
    const int*   nidx = (const int*)  d_in[2];
    const float* Wq   = (const float*)d_in[3];
    const float* Wk   = (const float*)d_in[4];
    const float* Wv   = (const float*)d_in[5];
    const float* Wa0  = (const float*)d_in[6];
    const float* Wa1  = (const float*)d_in[7];
    float* out = (float*)d_out;

    float* qb = (float*)d_ws;            // BL*128 each
    float* kb = qb + (size_t)BL * 128;
    float* vb = kb + (size_t)BL * 128;

    qkv_kernel<<<BL / 16, 256, 0, stream>>>(x, Wq, Wk, Wv, qb, kb, vb);
    attn_kernel<<<BL / 8, 512, 0, stream>>>(pos, nidx, qb, kb, vb, Wa0, Wa1, out);
}

// Round 2
// 475.762 us; speedup vs baseline: 1.7802x; 1.7802x over previous
//
#include <hip/hip_runtime.h>

#define BL 16384   // B*L
#define LQ 4096    // L

typedef unsigned int uint;
typedef __attribute__((ext_vector_type(8))) short short8;
typedef __attribute__((ext_vector_type(4))) float floatx4;

union F8 { uint u[4]; uint4 u4; short8 s; };

static __device__ __forceinline__ uint f2bf(float f) {
    uint x = __float_as_uint(f);
    x += 0x7fffu + ((x >> 16) & 1u);   // RTNE
    return x >> 16;
}
static __device__ __forceinline__ float bf2f(uint h) { return __uint_as_float(h << 16); }
static __device__ __forceinline__ uint pk(float lo, float hi) {
    return f2bf(lo) | (f2bf(hi) << 16);
}

// ============ Kernel 1: QKV projection, split-bf16 MFMA (fp32-accurate) ============
// grid (BL/64, 3), block 256. C = x[BL,128] @ W[128,128]; x=xh+xl, W=Wh+Wl;
// C ≈ xh*Wh + xh*Wl + xl*Wh  (drops xl*Wl ~ 2^-18 rel).
__global__ __launch_bounds__(256, 4) void qkv_mfma(
    const float* __restrict__ x, const float* __restrict__ Wq,
    const float* __restrict__ Wk, const float* __restrict__ Wv,
    float* __restrict__ qkvb)
{
    __shared__ uint4 wfh[4][8][64];   // hi frags: [ks][Nt][lane]
    __shared__ uint4 wfl[4][8][64];   // lo frags
    const int tid  = threadIdx.x;
    const int lane = tid & 63;
    const int w    = tid >> 6;
    const int q    = lane >> 4;
    const int c    = lane & 15;
    const int proj = blockIdx.y;
    const float* W = (proj == 0) ? Wq : (proj == 1) ? Wk : Wv;
    float* outb = qkvb + (size_t)proj * BL * 128;

    // prepack W -> hi/lo bf16 B-fragments: elem t = W[(ks*32+q*8+t)*128 + Nt*16+c]
    for (int e = tid; e < 32 * 64; e += 256) {
        const int f = e >> 6, ln = e & 63;
        const int ks = f >> 3, Nt = f & 7;
        const int lq = ln >> 4, lc = ln & 15;
        const float* wp = W + (ks * 32 + lq * 8) * 128 + Nt * 16 + lc;
        F8 hi, lo;
        #pragma unroll
        for (int j = 0; j < 4; ++j) {
            const float a = wp[(2 * j) * 128], b = wp[(2 * j + 1) * 128];
            const uint ha = f2bf(a), hb = f2bf(b);
            hi.u[j] = ha | (hb << 16);
            lo.u[j] = pk(a - bf2f(ha), b - bf2f(hb));
        }
        wfh[ks][Nt][ln] = hi.u4;
        wfl[ks][Nt][ln] = lo.u4;
    }
    __syncthreads();

    floatx4 acc[8];
    #pragma unroll
    for (int i = 0; i < 8; ++i) acc[i] = {0.f, 0.f, 0.f, 0.f};

    const int arow = blockIdx.x * 64 + w * 16 + c;   // A-frag row (m = c)
    #pragma unroll
    for (int ks = 0; ks < 4; ++ks) {
        const float* xp = x + arow * 128 + ks * 32 + q * 8;
        const float4 xa = ((const float4*)xp)[0];
        const float4 xb = ((const float4*)xp)[1];
        const float xv[8] = {xa.x, xa.y, xa.z, xa.w, xb.x, xb.y, xb.z, xb.w};
        F8 xh, xl;
        #pragma unroll
        for (int j = 0; j < 4; ++j) {
            const uint ha = f2bf(xv[2 * j]), hb = f2bf(xv[2 * j + 1]);
            xh.u[j] = ha | (hb << 16);
            xl.u[j] = pk(xv[2 * j] - bf2f(ha), xv[2 * j + 1] - bf2f(hb));
        }
        #pragma unroll
        for (int Nt = 0; Nt < 8; ++Nt) {
            F8 wh, wl;
            wh.u4 = wfh[ks][Nt][lane];
            wl.u4 = wfl[ks][Nt][lane];
            acc[Nt] = __builtin_amdgcn_mfma_f32_16x16x32_bf16(xh.s, wh.s, acc[Nt], 0, 0, 0);
            acc[Nt] = __builtin_amdgcn_mfma_f32_16x16x32_bf16(xh.s, wl.s, acc[Nt], 0, 0, 0);
            acc[Nt] = __builtin_amdgcn_mfma_f32_16x16x32_bf16(xl.s, wh.s, acc[Nt], 0, 0, 0);
        }
    }
    // C layout: row = q*4+r, col = c  (per 16x16 tile)
    const int orow = blockIdx.x * 64 + w * 16 + q * 4;
    #pragma unroll
    for (int Nt = 0; Nt < 8; ++Nt)
        #pragma unroll
        for (int r = 0; r < 4; ++r)
            outb[(orow + r) * 128 + Nt * 16 + c] = acc[Nt][r];
}

// ============ Kernel 2: fused neighbor-attention, MFMA ============
// grid BL/4, block 256 (4 waves); one wave per position, no barriers after init.
// GEMM1: H^T[64j x 32k] = Wa0^T (A, LDS frags) * T^T (B, built from global)
// transform via shuffles -> A2 (H) frags
// GEMM2 per N-tile: logits[32k x 16c] = H * Wa1, fused softmax + weighted-V.
__global__ __launch_bounds__(256, 4) void attn_mfma(
    const float* __restrict__ pos, const int* __restrict__ nn_idx,
    const float* __restrict__ qb, const float* __restrict__ kb,
    const float* __restrict__ vb, const float* __restrict__ Wa0,
    const float* __restrict__ Wa1, float* __restrict__ out)
{
    __shared__ uint4 wa0f[16][64];   // [Mt1*4+ks][lane]: Wa0^T A-frags
    __shared__ uint4 wa1f[16][64];   // [ks2*8+Nt2][lane]: Wa1 B-frags
    const int tid  = threadIdx.x;
    const int lane = tid & 63;
    const int w    = tid >> 6;
    const int q    = lane >> 4;
    const int c    = lane & 15;

    // Wa0^T frag elem t = Wa0[(ks*32+q*8+t)*64 + Mt1*16+c]   (A: m=j=lane&15? no: m index = c -> j)
    for (int e = tid; e < 16 * 64; e += 256) {
        const int f = e >> 6, ln = e & 63;
        const int Mt = f >> 2, ks = f & 3;
        const int lq = ln >> 4, lc = ln & 15;
        const float* wp = Wa0 + (ks * 32 + lq * 8) * 64 + Mt * 16 + lc;
        F8 v;
        #pragma unroll
        for (int j = 0; j < 4; ++j) v.u[j] = pk(wp[(2 * j) * 64], wp[(2 * j + 1) * 64]);
        wa0f[f][ln] = v.u4;
    }
    // Wa1 frag elem t = Wa1[(ks2*32+q*8+t)*128 + Nt2*16+c]
    for (int e = tid; e < 16 * 64; e += 256) {
        const int f = e >> 6, ln = e & 63;
        const int ks = f >> 3, Nt = f & 7;
        const int lq = ln >> 4, lc = ln & 15;
        const float* wp = Wa1 + (ks * 32 + lq * 8) * 128 + Nt * 16 + lc;
        F8 v;
        #pragma unroll
        for (int j = 0; j < 4; ++j) v.u[j] = pk(wp[(2 * j) * 128], wp[(2 * j + 1) * 128]);
        wa1f[f][ln] = v.u4;
    }
    __syncthreads();

    const int p     = blockIdx.x * 4 + w;
    const int bbase = (p >> 12) << 12;           // b * L

    const int idx0 = nn_idx[p * 32 + c];         // neighbor c
    const int idx1 = nn_idx[p * 32 + 16 + c];    // neighbor 16+c
    const int r0   = (bbase + idx0) * 128;
    const int r1   = (bbase + idx1) * 128;
    const int pr0  = (p * 32 + c) * 128;
    const int pr1  = pr0 + 16 * 128;

    // ---- GEMM1 ----
    floatx4 acc1[4][2];
    #pragma unroll
    for (int i = 0; i < 4; ++i) { acc1[i][0] = {0.f,0.f,0.f,0.f}; acc1[i][1] = {0.f,0.f,0.f,0.f}; }

    #pragma unroll
    for (int ks = 0; ks < 4; ++ks) {
        const int u0 = ks * 32 + q * 8;
        const float4 qa = *(const float4*)(qb + p * 128 + u0);
        const float4 qc = *(const float4*)(qb + p * 128 + u0 + 4);
        F8 bfrag[2];
        #pragma unroll
        for (int Nt = 0; Nt < 2; ++Nt) {
            const int kr = (Nt == 0 ? r0 : r1) + u0;
            const int pr = (Nt == 0 ? pr0 : pr1) + u0;
            const float4 ka = *(const float4*)(kb + kr);
            const float4 kc = *(const float4*)(kb + kr + 4);
            const float4 pa = *(const float4*)(pos + pr);
            const float4 pc = *(const float4*)(pos + pr + 4);
            const float t0 = qa.x - ka.x + pa.x, t1 = qa.y - ka.y + pa.y;
            const float t2 = qa.z - ka.z + pa.z, t3 = qa.w - ka.w + pa.w;
            const float t4 = qc.x - kc.x + pc.x, t5 = qc.y - kc.y + pc.y;
            const float t6 = qc.z - kc.z + pc.z, t7 = qc.w - kc.w + pc.w;
            bfrag[Nt].u[0] = pk(t0, t1); bfrag[Nt].u[1] = pk(t2, t3);
            bfrag[Nt].u[2] = pk(t4, t5); bfrag[Nt].u[3] = pk(t6, t7);
        }
        #pragma unroll
        for (int Mt = 0; Mt < 4; ++Mt) {
            F8 a1; a1.u4 = wa0f[Mt * 4 + ks][lane];
            acc1[Mt][0] = __builtin_amdgcn_mfma_f32_16x16x32_bf16(a1.s, bfrag[0].s, acc1[Mt][0], 0, 0, 0);
            acc1[Mt][1] = __builtin_amdgcn_mfma_f32_16x16x32_bf16(a1.s, bfrag[1].s, acc1[Mt][1], 0, 0, 0);
        }
    }

    // ---- transform: C1-layout H^T -> A2 (H) fragments, with relu ----
    // dest elem t of frag (Mt2,ks): j = ks*32+q*8+t, src tile Mt1 = 2ks+(q>>1),
    // src lane = c + 16*((q&1)*2 + (t>>2)), src reg = t&3.
    F8 a2[2][2];
    #pragma unroll
    for (int Mt2 = 0; Mt2 < 2; ++Mt2) {
        #pragma unroll
        for (int ks = 0; ks < 2; ++ks) {
            float vv[8];
            #pragma unroll
            for (int t = 0; t < 8; ++t) {
                const int sl = c + 16 * ((q & 1) * 2 + (t >> 2));
                const float vA = __shfl(acc1[2 * ks + 0][Mt2][t & 3], sl, 64);
                const float vB = __shfl(acc1[2 * ks + 1][Mt2][t & 3], sl, 64);
                vv[t] = fmaxf((q < 2) ? vA : vB, 0.f);
            }
            #pragma unroll
            for (int j = 0; j < 4; ++j) a2[Mt2][ks].u[j] = pk(vv[2 * j], vv[2 * j + 1]);
        }
    }

    // ---- per-row (neighbor) base addresses for the weighted-V phase ----
    int vrow[2][4], prow[2][4];
    #pragma unroll
    for (int Mt2 = 0; Mt2 < 2; ++Mt2)
        #pragma unroll
        for (int r = 0; r < 4; ++r) {
            const int knb  = Mt2 * 16 + q * 4 + r;
            const int sidx = __shfl(Mt2 == 0 ? idx0 : idx1, q * 4 + r, 64);
            vrow[Mt2][r] = (bbase + sidx) * 128;
            prow[Mt2][r] = (p * 32 + knb) * 128;
        }

    // ---- GEMM2 + fused softmax + weighted sum, per N-tile (16 cols) ----
    #pragma unroll
    for (int Nt2 = 0; Nt2 < 8; ++Nt2) {
        F8 b0, b1;
        b0.u4 = wa1f[Nt2][lane];        // ks2 = 0
        b1.u4 = wa1f[8 + Nt2][lane];    // ks2 = 1
        floatx4 a2c[2];
        a2c[0] = {0.f,0.f,0.f,0.f}; a2c[1] = {0.f,0.f,0.f,0.f};
        #pragma unroll
        for (int Mt2 = 0; Mt2 < 2; ++Mt2) {
            a2c[Mt2] = __builtin_amdgcn_mfma_f32_16x16x32_bf16(a2[Mt2][0].s, b0.s, a2c[Mt2], 0, 0, 0);
            a2c[Mt2] = __builtin_amdgcn_mfma_f32_16x16x32_bf16(a2[Mt2][1].s, b1.s, a2c[Mt2], 0, 0, 0);
        }
        const int cg = Nt2 * 16 + c;
        float se = 0.f, ov = 0.f;
        #pragma unroll
        for (int Mt2 = 0; Mt2 < 2; ++Mt2)
            #pragma unroll
            for (int r = 0; r < 4; ++r) {
                const float e  = __expf(a2c[Mt2][r]);
                const float vp = vb[vrow[Mt2][r] + cg] + pos[prow[Mt2][r] + cg];
                se += e;
                ov = fmaf(e, vp, ov);
            }
        se += __shfl_xor(se, 16, 64); ov += __shfl_xor(ov, 16, 64);
        se += __shfl_xor(se, 32, 64); ov += __shfl_xor(ov, 32, 64);
        if (q == 0) out[p * 128 + cg] = ov / se;
    }
}

extern "C" void kernel_launch(void* const* d_in, const int* in_sizes, int n_in,
                              void* d_out, int out_size, void* d_ws, size_t ws_size,
                              hipStream_t stream) {
    const float* x    = (const float*)d_in[0];
    const float* pos  = (const float*)d_in[1];
    const int*   nidx = (const int*)  d_in[2];
    const float* Wq   = (const float*)d_in[3];
    const float* Wk   = (const float*)d_in[4];
    const float* Wv   = (const float*)d_in[5];
    const float* Wa0  = (const float*)d_in[6];
    const float* Wa1  = (const float*)d_in[7];
    float* outp = (float*)d_out;

    float* qkvb = (float*)d_ws;   // q | k | v, each BL*128 f32
    const float* qbp = qkvb;
    const float* kbp = qkvb + (size_t)BL * 128;
    const float* vbp = qkvb + (size_t)2 * BL * 128;

    qkv_mfma<<<dim3(BL / 64, 3), 256, 0, stream>>>(x, Wq, Wk, Wv, qkvb);
    attn_mfma<<<BL / 4, 256, 0, stream>>>(pos, nidx, qbp, kbp, vbp, Wa0, Wa1, outp);
}